// Round 16
// baseline (166.787 us; speedup 1.0000x reference)
//
#include <hip/hip_runtime.h>
#include <hip/hip_bf16.h>

// ---------- types ----------
typedef __attribute__((ext_vector_type(8))) short bf8_t;   // 8 bf16 (4 VGPRs)
typedef __attribute__((ext_vector_type(4))) float f4_t;    // MFMA accumulator
typedef __attribute__((ext_vector_type(2))) unsigned int u2_t;
typedef __attribute__((ext_vector_type(4))) unsigned int u4_t;

#define MFMA16(a, b, c) __builtin_amdgcn_mfma_f32_16x16x32_bf16((a), (b), (c), 0, 0, 0)

static __device__ inline unsigned short f2bf(float f) {
    unsigned int u = __float_as_uint(f);
    unsigned int r = 0x7fffu + ((u >> 16) & 1u);
    return (unsigned short)((u + r) >> 16);
}

// guaranteed single-instruction exp2
static __device__ inline float exp2_fast(float x) {
    float r;
    asm("v_exp_f32 %0, %1" : "=v"(r) : "v"(x));
    return r;
}

// pack 2 fp32 -> 2 bf16 in one u32
static __device__ inline unsigned int cvtpk_bf16(float lo, float hi) {
    unsigned int r;
    asm("v_cvt_pk_bf16_f32 %0, %1, %2" : "=v"(r) : "v"(lo), "v"(hi));
    return r;
}

// async global->LDS, 16B per lane; dest = wave-uniform base + lane*16
static __device__ inline void gload16(const void* g, void* l) {
    __builtin_amdgcn_global_load_lds(
        (const __attribute__((address_space(1))) unsigned int*)g,
        (__attribute__((address_space(3))) unsigned int*)l, 16, 0, 0);
}

// ---------- fused prep: x cvt (jobs 0..8191) | W transpose (8192..12287) | mask bias (12288) ----------
__global__ __launch_bounds__(256) void k_prep(
    const float* __restrict__ x, unsigned short* __restrict__ xb,
    const float* __restrict__ Wq, const float* __restrict__ Wk,
    const float* __restrict__ Wv, const float* __restrict__ Wo,
    unsigned short* __restrict__ WT,
    const void* __restrict__ maskp, float* __restrict__ fbias)
{
    __shared__ float tile[32][33];
    __shared__ int s_int, s_flt;
    const int tid = threadIdx.x;
    const int job = blockIdx.x;

    if (job < 8192) {
        // fp32 -> bf16 convert (x), 4 elems/thread
        int i = job * 256 + tid;
        float4 v = ((const float4*)x)[i];
        ushort4 o;
        o.x = f2bf(v.x); o.y = f2bf(v.y); o.z = f2bf(v.z); o.w = f2bf(v.w);
        ((ushort4*)xb)[i] = o;
    } else if (job < 12288) {
        // W [K][N] -> WT [N][K] bf16
        int jj = job - 8192;
        int z  = jj >> 10;
        int by = (jj >> 5) & 31;
        int bx = jj & 31;
        int tx = tid & 31, ty = tid >> 5;        // 32 x 8
        const float* W = (z == 0) ? Wq : (z == 1) ? Wk : (z == 2) ? Wv : Wo;
        unsigned short* out = WT + (size_t)z * 1024 * 1024;
        int n_r = bx * 32 + tx;
        int k_r = by * 32 + ty;
        #pragma unroll
        for (int j = 0; j < 32; j += 8)
            tile[ty + j][tx] = W[(size_t)(k_r + j) * 1024 + n_r];
        __syncthreads();
        int k_w = by * 32 + tx;
        int n_w = bx * 32 + ty;
        #pragma unroll
        for (int j = 0; j < 32; j += 8)
            out[(size_t)(n_w + j) * 1024 + k_w] = f2bf(tile[tx][ty + j]);
    } else {
        // mask probe + additive-bias build
        const unsigned int* mw = (const unsigned int*)maskp;
        if (tid == 0) { s_int = 1; s_flt = 1; }
        __syncthreads();
        int li = 1, lf = 1;
        for (int i = tid; i < 2048; i += 256) {
            unsigned int v = mw[i];
            if (v != 0u && v != 1u) li = 0;
            if (v != 0u && v != 0x3F800000u) lf = 0;
        }
        if (!li) atomicAnd(&s_int, 0);
        if (!lf) atomicAnd(&s_flt, 0);
        __syncthreads();
        const int flag = s_int ? 0 : (s_flt ? 1 : 2);
        const int*           mi = (const int*)maskp;
        const float*         mf = (const float*)maskp;
        const unsigned char* mb = (const unsigned char*)maskp;
        for (int i = tid; i < 8192; i += 256) {
            bool m = (flag == 0) ? (mi[i] != 0) : (flag == 1) ? (mf[i] != 0.0f) : (mb[i] != 0);
            fbias[i] = m ? -1e30f : 0.0f;
        }
    }
}

// ---------- GEMM: C[8192][1024] = A_bf16 @ WT^T (+bias)  (R15 structure, unchanged) ----------
template <int MODE>
__global__ __launch_bounds__(256) void k_gemm(
    const unsigned short* __restrict__ A,
    const unsigned short* __restrict__ WTb,
    const float* __restrict__ b0, const float* __restrict__ b1, const float* __restrict__ b2,
    void* __restrict__ outp, void* __restrict__ outp2)
{
    __shared__ __align__(16) unsigned short SH[32768];   // 64 KiB: 2 x (A 16KB + B 16KB); epilogue overlay
    const int tid  = threadIdx.x;
    const int lane = tid & 63;
    const int w    = tid >> 6;
    const int wr   = w >> 1, wc = w & 1;
    const int lg   = lane >> 4, lr = lane & 15;
    const int lg4  = lg * 4;

    // XCD-locality decode (R13)
    const int id   = blockIdx.x;
    const int xcd  = id & 7;
    const int j    = id >> 3;
    const int ncol = j >> 3;
    const int by   = xcd * 8 + (j & 7);
    const int z    = (MODE == 0) ? (ncol >> 3) : 0;
    const int bm   = by * 128;
    const int bn   = ((MODE == 0) ? (ncol & 7) : ncol) * 128;
    const unsigned short* WT = WTb + (MODE == 0 ? (size_t)z * (1024 * 1024) : 0);

    f4_t acc[4][4];
    const f4_t z4 = {0.f, 0.f, 0.f, 0.f};
    #pragma unroll
    for (int i = 0; i < 4; ++i)
        #pragma unroll
        for (int jj = 0; jj < 4; ++jj) acc[i][jj] = z4;

    int strow[4], stcol[4];
    #pragma unroll
    for (int p = 0; p < 4; ++p) {
        int o = p * 4096 + tid * 16;
        strow[p] = o >> 7;
        stcol[p] = (o & 127) ^ ((strow[p] & 7) << 4);   // inverse swizzle on global src
    }

    auto stage = [&](int buf, int k0) {   // 8 gload16 per thread
        char* base = (char*)SH + buf * 32768;
        #pragma unroll
        for (int p = 0; p < 4; ++p) {
            int o = p * 4096 + tid * 16;
            gload16((const char*)(A  + (size_t)(bm + strow[p]) * 1024 + k0) + stcol[p], base + o);
            gload16((const char*)(WT + (size_t)(bn + strow[p]) * 1024 + k0) + stcol[p], base + 16384 + o);
        }
    };

    const int swz = (lr & 7) << 4;
    auto compute = [&](int buf) {
        const char* base = (const char*)SH + buf * 32768;
        bf8_t af[2][4], bfv[2][4];
        #pragma unroll
        for (int kk = 0; kk < 2; ++kk) {
            int col = (kk * 64 + lg * 16) ^ swz;
            #pragma unroll
            for (int i = 0; i < 4; ++i)
                af[kk][i] = *(const bf8_t*)(base + (wr * 64 + i * 16 + lr) * 128 + col);
            #pragma unroll
            for (int jj = 0; jj < 4; ++jj)
                bfv[kk][jj] = *(const bf8_t*)(base + 16384 + (wc * 64 + jj * 16 + lr) * 128 + col);
        }
        __builtin_amdgcn_s_setprio(1);
        #pragma unroll
        for (int kk = 0; kk < 2; ++kk)
            #pragma unroll
            for (int i = 0; i < 4; ++i)
                #pragma unroll
                for (int jj = 0; jj < 4; ++jj)
                    acc[i][jj] = MFMA16(af[kk][i], bfv[kk][jj], acc[i][jj]);
        __builtin_amdgcn_s_setprio(0);
    };

    stage(0, 0);
    __syncthreads();

    #pragma unroll 1
    for (int tt = 0; tt < 8; ++tt) {
        stage(1, (2 * tt + 1) * 64);
        compute(0);
        __syncthreads();
        if (tt < 7) stage(0, (2 * tt + 2) * 64);
        compute(1);
        __syncthreads();
    }

    if (MODE == 0) {
        const float* bias = (z == 0) ? b0 : (z == 1) ? b1 : b2;
        const float sc = (z == 0) ? 0.18033688011112042f : 1.0f; // 0.125*log2(e)
        const int bb = bm >> 11;
        const int sb = bm & 2047;

        if (z < 2) {
            #pragma unroll
            for (int i = 0; i < 4; ++i)
                #pragma unroll
                for (int jj = 0; jj < 4; ++jj) {
                    int c = wc * 64 + jj * 16 + lr;
                    float bcol = bias[bn + c];
                    #pragma unroll
                    for (int r = 0; r < 4; ++r) {
                        int s = wr * 64 + i * 16 + lg4 + r;
                        SH[s * 136 + c] = f2bf((acc[i][jj][r] + bcol) * sc);
                    }
                }
            __syncthreads();
            unsigned short* O = (unsigned short*)outp + (size_t)z * (8192 * 1024);
            #pragma unroll
            for (int it = 0; it < 8; ++it) {
                int idx = it * 256 + tid;
                int hh  = idx >> 10;
                int rem = idx & 1023;
                int ss  = rem >> 3;
                int cc  = rem & 7;
                u4_t v = *(const u4_t*)&SH[ss * 136 + hh * 64 + cc * 8];
                int hq = (bn >> 6) + hh;
                *(u4_t*)(O + (((size_t)(bb * 16 + hq)) * 2048 + sb + ss) * 64 + cc * 8) = v;
            }
        } else {
            // V^T: stage TRANSPOSED + key-permuted: SH[d_local][sp]
            #pragma unroll
            for (int i = 0; i < 4; ++i) {
                int spb = wr * 64 + 32 * (i >> 1) + 8 * lg + 4 * (i & 1);
                #pragma unroll
                for (int jj = 0; jj < 4; ++jj) {
                    int c = wc * 64 + jj * 16 + lr;
                    float bcol = bias[bn + c];
                    #pragma unroll
                    for (int r = 0; r < 4; ++r)
                        SH[c * 136 + spb + r] = f2bf(acc[i][jj][r] + bcol);
                }
            }
            __syncthreads();
            unsigned short* OT = (unsigned short*)outp2;
            #pragma unroll
            for (int it = 0; it < 8; ++it) {
                int idx  = it * 256 + tid;
                int drow = idx >> 4;
                int cc   = idx & 15;
                u4_t v = *(const u4_t*)&SH[drow * 136 + cc * 8];
                int dcol = bn + drow;
                int hq = dcol >> 6, dh = dcol & 63;
                *(u4_t*)(OT + (((size_t)(bb * 16 + hq)) * 64 + dh) * 2048 + sb + cc * 8) = v;
            }
        }
    } else {
        float* O = (float*)outp;
        float* SF = (float*)SH;
        #pragma unroll
        for (int hhalf = 0; hhalf < 2; ++hhalf) {
            if (wr == hhalf) {
                #pragma unroll
                for (int i = 0; i < 4; ++i)
                    #pragma unroll
                    for (int jj = 0; jj < 4; ++jj) {
                        int c = wc * 64 + jj * 16 + lr;
                        float bcol = b0[bn + c];
                        #pragma unroll
                        for (int r = 0; r < 4; ++r)
                            SF[(i * 16 + lg4 + r) * 132 + c] = acc[i][jj][r] + bcol;
                    }
            }
            __syncthreads();
            #pragma unroll
            for (int it = 0; it < 8; ++it) {
                int idx = it * 256 + tid;
                int ss  = idx >> 5;
                int cc  = idx & 31;
                u4_t v = *(const u4_t*)&SF[ss * 132 + cc * 4];
                *(u4_t*)(O + (size_t)(bm + hhalf * 64 + ss) * 1024 + bn + cc * 4) = v;
            }
            __syncthreads();
        }
    }
}

// ---------- flash attention: direct-exp2, MFMA denom, KVBLK=128 (2x64 halves) ----------
// Staging/compute layouts identical to R15; each buffer holds TWO 64-key halves so
// the barrier pair amortizes over 128 keys (half the barrier+drain count).
// grid 512: 8 q-tiles x 64 heads, XCD-grouped. 4 waves x 64 q-rows (4 subtiles).
__global__ __launch_bounds__(256, 2) void k_attn(
    const unsigned short* __restrict__ Q,    // [64][2048][64], pre-scaled by 0.125*log2e
    const unsigned short* __restrict__ K,    // [64][2048][64]
    const unsigned short* __restrict__ VT,   // [64][64][2048], key-permuted per 64-block
    const float* __restrict__ fbias,         // [4][2048] 0/-1e30
    unsigned short* __restrict__ O)          // [8192][1024]
{
    __shared__ __align__(16) unsigned short Kls[2][2][64][64];  // [buf][half][key][d]
    __shared__ __align__(16) unsigned short Vls[2][2][64][64];  // [buf][half][d][pos]
    const int tid  = threadIdx.x;
    const int lane = tid & 63;
    const int w    = tid >> 6;
    const int lg   = lane >> 4, lr = lane & 15;
    const int lg4  = lg * 4;

    const int id = blockIdx.x;
    const int bh = (id & 7) * 8 + ((id >> 3) & 7);   // XCD (id&7) owns 8 heads
    const int qt = id >> 6;                           // 0..7
    const int b  = bh >> 4, h = bh & 15;
    const int q0 = qt * 256 + w * 64;
    const size_t base = (size_t)bh * (2048 * 64);

    const char* Kbase = (const char*)(K + base);
    const char* Vbase = (const char*)(VT + (size_t)bh * (64 * 2048));

    int srow[2], scol[2];
    #pragma unroll
    for (int p = 0; p < 2; ++p) {
        int o = p * 4096 + tid * 16;
        srow[p] = o >> 7;
        scol[p] = (o & 127) ^ ((srow[p] & 7) << 4);   // inverse swizzle on global src
    }

    auto stage_half = [&](int buf, int half, int k0h) {
        #pragma unroll
        for (int p = 0; p < 2; ++p) {
            int o = p * 4096 + tid * 16;
            gload16(Kbase + (size_t)(k0h + srow[p]) * 128 + scol[p],
                    (char*)&Kls[buf][half][0][0] + o);
            gload16(Vbase + (size_t)srow[p] * 4096 + (size_t)k0h * 2 + scol[p],
                    (char*)&Vls[buf][half][0][0] + o);
        }
    };
    auto stage = [&](int buf, int k0) {
        stage_half(buf, 0, k0);
        stage_half(buf, 1, k0 + 64);
    };

    // Q fragments, 4 subtiles (B-operand: lane holds Q[q=lr][dh=lg*8..])
    bf8_t qf[4][2];
    #pragma unroll
    for (int sub = 0; sub < 4; ++sub) {
        const unsigned short* qp = Q + base + (size_t)(q0 + sub * 16 + lr) * 64 + lg * 8;
        qf[sub][0] = *(const bf8_t*)qp;
        qf[sub][1] = *(const bf8_t*)(qp + 32);
    }

    const f4_t z4 = {0.f, 0.f, 0.f, 0.f};
    f4_t oacc[4][4];                 // [sub][nf]: O^T[d=nf*16+lg4+r][q=lr]
    #pragma unroll
    for (int sub = 0; sub < 4; ++sub)
        #pragma unroll
        for (int nf = 0; nf < 4; ++nf) oacc[sub][nf] = z4;
    f4_t lacc[4] = {z4, z4, z4, z4}; // denominator via MFMA(ones, P)

    u4_t uones = {0x3F803F80u, 0x3F803F80u, 0x3F803F80u, 0x3F803F80u};
    const bf8_t ones8 = __builtin_bit_cast(bf8_t, uones);

    const float* fb = fbias + b * 2048 + lg4;
    const int sw = (lr & 7) << 4;
    const int cA = (lg * 16) ^ sw;          // K frag cols
    const int cB = (64 + lg * 16) ^ sw;
    const int vA = (16 * lg) ^ sw;          // V frag cols (chunk 0 / 1)
    const int vB = (64 + 16 * lg) ^ sw;

    // direct softmax numerator: P = exp2(s); no max, no rescale, no cross-lane
    auto sm = [&](f4_t (&s)[4], u4_t (&pf)[2]) {
        #pragma unroll
        for (int c2 = 0; c2 < 2; ++c2) {
            float e0 = exp2_fast(s[2*c2][0]);
            float e1 = exp2_fast(s[2*c2][1]);
            float e2 = exp2_fast(s[2*c2][2]);
            float e3 = exp2_fast(s[2*c2][3]);
            float e4 = exp2_fast(s[2*c2+1][0]);
            float e5 = exp2_fast(s[2*c2+1][1]);
            float e6 = exp2_fast(s[2*c2+1][2]);
            float e7 = exp2_fast(s[2*c2+1][3]);
            u4_t u;
            u.x = cvtpk_bf16(e0, e1);
            u.y = cvtpk_bf16(e2, e3);
            u.z = cvtpk_bf16(e4, e5);
            u.w = cvtpk_bf16(e6, e7);
            pf[c2] = u;
        }
    };

    // one 64-key half; cur/half literal -> LDS addresses fold at compile time
    auto tile_body = [&](int cur, int half, int k0) {
        f4_t cb[4];
        #pragma unroll
        for (int mf = 0; mf < 4; ++mf)
            cb[mf] = *(const f4_t*)(fb + k0 + mf * 16);

        bf8_t kf[4][2];
        #pragma unroll
        for (int mf = 0; mf < 4; ++mf) {
            const char* kr = (const char*)&Kls[cur][half][mf * 16 + lr][0];
            kf[mf][0] = *(const bf8_t*)(kr + cA);
            kf[mf][1] = *(const bf8_t*)(kr + cB);
        }
        bf8_t vf[4][2];
        #pragma unroll
        for (int nf = 0; nf < 4; ++nf) {
            const char* vr = (const char*)&Vls[cur][half][nf * 16 + lr][0];
            vf[nf][0] = *(const bf8_t*)(vr + vA);
            vf[nf][1] = *(const bf8_t*)(vr + vB);
        }

        // per-sub {QK -> exp2 -> PV}: sm(sub+1) VALU overlaps PV(sub) MFMA
        #pragma unroll
        for (int sub = 0; sub < 4; ++sub) {
            f4_t s[4];
            __builtin_amdgcn_s_setprio(1);
            #pragma unroll
            for (int mf = 0; mf < 4; ++mf)
                s[mf] = MFMA16(kf[mf][1], qf[sub][1], MFMA16(kf[mf][0], qf[sub][0], cb[mf]));
            __builtin_amdgcn_s_setprio(0);

            u4_t pf[2];
            sm(s, pf);

            __builtin_amdgcn_s_setprio(1);
            #pragma unroll
            for (int c = 0; c < 2; ++c) {
                bf8_t pb = __builtin_bit_cast(bf8_t, pf[c]);
                lacc[sub] = MFMA16(ones8, pb, lacc[sub]);
                #pragma unroll
                for (int nf = 0; nf < 4; ++nf)
                    oacc[sub][nf] = MFMA16(vf[nf][c], pb, oacc[sub][nf]);
            }
            __builtin_amdgcn_s_setprio(0);
        }
    };

    stage(0, 0);
    __syncthreads();

    #pragma unroll 1
    for (int tt = 0; tt < 8; ++tt) {           // 16 tiles of 128 keys
        stage(1, (2 * tt + 1) * 128);
        tile_body(0, 0, 2 * tt * 128);
        tile_body(0, 1, 2 * tt * 128 + 64);
        __syncthreads();
        if (tt < 7) stage(0, (2 * tt + 2) * 128);
        tile_body(1, 0, (2 * tt + 1) * 128);
        tile_body(1, 1, (2 * tt + 1) * 128 + 64);
        __syncthreads();
    }

    // normalize + write [B,S,D] bf16 (lane owns q=lr; no cross-lane reduce)
    #pragma unroll
    for (int sub = 0; sub < 4; ++sub) {
        float inv = 1.0f / lacc[sub][0];
        int qrow = q0 + sub * 16 + lr;
        size_t ob = ((size_t)(b * 2048 + qrow)) * 1024 + h * 64 + lg4;
        #pragma unroll
        for (int nf = 0; nf < 4; ++nf) {
            u2_t uo;
            uo.x = cvtpk_bf16(oacc[sub][nf][0] * inv, oacc[sub][nf][1] * inv);
            uo.y = cvtpk_bf16(oacc[sub][nf][2] * inv, oacc[sub][nf][3] * inv);
            *(u2_t*)(O + ob + nf * 16) = uo;
        }
    }
}

// ---------- launch ----------
extern "C" void kernel_launch(void* const* d_in, const int* in_sizes, int n_in,
                              void* d_out, int out_size, void* d_ws, size_t ws_size,
                              hipStream_t stream) {
    const float* x  = (const float*)d_in[0];
    const void*  mask = d_in[1];
    const float* Wq = (const float*)d_in[2];
    const float* bq = (const float*)d_in[3];
    const float* Wk = (const float*)d_in[4];
    const float* bk = (const float*)d_in[5];
    const float* Wv = (const float*)d_in[6];
    const float* bv = (const float*)d_in[7];
    const float* Wo = (const float*)d_in[8];
    const float* bo = (const float*)d_in[9];

    char* ws = (char*)d_ws;
    float*          fbias = (float*)(ws + 1024);
    unsigned short* xb    = (unsigned short*)(ws + 65536);                // 16 MiB
    unsigned short* wT    = (unsigned short*)(ws + 65536 + 16777216);     // 8 MiB
    unsigned short* qkv   = (unsigned short*)(ws + 65536 + 25165824);     // 48 MiB (Q,K,VT)
    unsigned short* attnb = (unsigned short*)(ws + 65536 + 75497472);     // 16 MiB

    unsigned short* Qb = qkv;
    unsigned short* Kb = qkv + 8388608;
    unsigned short* VT = qkv + 16777216;   // written (key-permuted) by GEMM z==2 epilogue

    k_prep<<<12289, 256, 0, stream>>>(x, xb, Wq, Wk, Wv, Wo, wT, mask, fbias);
    k_gemm<0><<<1536, 256, 0, stream>>>(xb, wT, bq, bk, bv, (void*)qkv, (void*)VT);
    k_attn<<<512, 256, 0, stream>>>(Qb, Kb, VT, fbias, attnb);
    k_gemm<1><<<512, 256, 0, stream>>>(attnb, wT + 3145728, bo, bo, bo, d_out, nullptr);
}

// Round 18
// 166.716 us; speedup vs baseline: 1.0004x; 1.0004x over previous
//
#include <hip/hip_runtime.h>
#include <hip/hip_bf16.h>

// ---------- types ----------
typedef __attribute__((ext_vector_type(8))) short bf8_t;   // 8 bf16 (4 VGPRs)
typedef __attribute__((ext_vector_type(4))) float f4_t;    // MFMA accumulator
typedef __attribute__((ext_vector_type(2))) unsigned int u2_t;
typedef __attribute__((ext_vector_type(4))) unsigned int u4_t;

#define MFMA16(a, b, c) __builtin_amdgcn_mfma_f32_16x16x32_bf16((a), (b), (c), 0, 0, 0)

static __device__ inline unsigned short f2bf(float f) {
    unsigned int u = __float_as_uint(f);
    unsigned int r = 0x7fffu + ((u >> 16) & 1u);
    return (unsigned short)((u + r) >> 16);
}

// guaranteed single-instruction exp2
static __device__ inline float exp2_fast(float x) {
    float r;
    asm("v_exp_f32 %0, %1" : "=v"(r) : "v"(x));
    return r;
}

// pack 2 fp32 -> 2 bf16 in one u32
static __device__ inline unsigned int cvtpk_bf16(float lo, float hi) {
    unsigned int r;
    asm("v_cvt_pk_bf16_f32 %0, %1, %2" : "=v"(r) : "v"(lo), "v"(hi));
    return r;
}

// async global->LDS, 16B per lane; dest = wave-uniform base + lane*16
static __device__ inline void gload16(const void* g, void* l) {
    __builtin_amdgcn_global_load_lds(
        (const __attribute__((address_space(1))) unsigned int*)g,
        (__attribute__((address_space(3))) unsigned int*)l, 16, 0, 0);
}

// ---------- fused prep: x cvt (jobs 0..8191) | W transpose (8192..12287) | mask bias (12288) ----------
__global__ __launch_bounds__(256) void k_prep(
    const float* __restrict__ x, unsigned short* __restrict__ xb,
    const float* __restrict__ Wq, const float* __restrict__ Wk,
    const float* __restrict__ Wv, const float* __restrict__ Wo,
    unsigned short* __restrict__ WT,
    const void* __restrict__ maskp, float* __restrict__ fbias)
{
    __shared__ float tile[32][33];
    __shared__ int s_int, s_flt;
    const int tid = threadIdx.x;
    const int job = blockIdx.x;

    if (job < 8192) {
        int i = job * 256 + tid;
        float4 v = ((const float4*)x)[i];
        ushort4 o;
        o.x = f2bf(v.x); o.y = f2bf(v.y); o.z = f2bf(v.z); o.w = f2bf(v.w);
        ((ushort4*)xb)[i] = o;
    } else if (job < 12288) {
        int jj = job - 8192;
        int z  = jj >> 10;
        int by = (jj >> 5) & 31;
        int bx = jj & 31;
        int tx = tid & 31, ty = tid >> 5;        // 32 x 8
        const float* W = (z == 0) ? Wq : (z == 1) ? Wk : (z == 2) ? Wv : Wo;
        unsigned short* out = WT + (size_t)z * 1024 * 1024;
        int n_r = bx * 32 + tx;
        int k_r = by * 32 + ty;
        #pragma unroll
        for (int j = 0; j < 32; j += 8)
            tile[ty + j][tx] = W[(size_t)(k_r + j) * 1024 + n_r];
        __syncthreads();
        int k_w = by * 32 + tx;
        int n_w = bx * 32 + ty;
        #pragma unroll
        for (int j = 0; j < 32; j += 8)
            out[(size_t)(n_w + j) * 1024 + k_w] = f2bf(tile[tx][ty + j]);
    } else {
        const unsigned int* mw = (const unsigned int*)maskp;
        if (tid == 0) { s_int = 1; s_flt = 1; }
        __syncthreads();
        int li = 1, lf = 1;
        for (int i = tid; i < 2048; i += 256) {
            unsigned int v = mw[i];
            if (v != 0u && v != 1u) li = 0;
            if (v != 0u && v != 0x3F800000u) lf = 0;
        }
        if (!li) atomicAnd(&s_int, 0);
        if (!lf) atomicAnd(&s_flt, 0);
        __syncthreads();
        const int flag = s_int ? 0 : (s_flt ? 1 : 2);
        const int*           mi = (const int*)maskp;
        const float*         mf = (const float*)maskp;
        const unsigned char* mb = (const unsigned char*)maskp;
        for (int i = tid; i < 8192; i += 256) {
            bool m = (flag == 0) ? (mi[i] != 0) : (flag == 1) ? (mf[i] != 0.0f) : (mb[i] != 0);
            fbias[i] = m ? -1e30f : 0.0f;
        }
    }
}

// ---------- GEMM: C[8192][1024] = A_bf16 @ WT^T (+bias)  (R15 structure, unchanged) ----------
template <int MODE>
__global__ __launch_bounds__(256) void k_gemm(
    const unsigned short* __restrict__ A,
    const unsigned short* __restrict__ WTb,
    const float* __restrict__ b0, const float* __restrict__ b1, const float* __restrict__ b2,
    void* __restrict__ outp, void* __restrict__ outp2)
{
    __shared__ __align__(16) unsigned short SH[32768];   // 64 KiB: 2 x (A 16KB + B 16KB); epilogue overlay
    const int tid  = threadIdx.x;
    const int lane = tid & 63;
    const int w    = tid >> 6;
    const int wr   = w >> 1, wc = w & 1;
    const int lg   = lane >> 4, lr = lane & 15;
    const int lg4  = lg * 4;

    const int id   = blockIdx.x;
    const int xcd  = id & 7;
    const int j    = id >> 3;
    const int ncol = j >> 3;
    const int by   = xcd * 8 + (j & 7);
    const int z    = (MODE == 0) ? (ncol >> 3) : 0;
    const int bm   = by * 128;
    const int bn   = ((MODE == 0) ? (ncol & 7) : ncol) * 128;
    const unsigned short* WT = WTb + (MODE == 0 ? (size_t)z * (1024 * 1024) : 0);

    f4_t acc[4][4];
    const f4_t z4 = {0.f, 0.f, 0.f, 0.f};
    #pragma unroll
    for (int i = 0; i < 4; ++i)
        #pragma unroll
        for (int jj = 0; jj < 4; ++jj) acc[i][jj] = z4;

    int strow[4], stcol[4];
    #pragma unroll
    for (int p = 0; p < 4; ++p) {
        int o = p * 4096 + tid * 16;
        strow[p] = o >> 7;
        stcol[p] = (o & 127) ^ ((strow[p] & 7) << 4);   // inverse swizzle on global src
    }

    auto stage = [&](int buf, int k0) {   // 8 gload16 per thread
        char* base = (char*)SH + buf * 32768;
        #pragma unroll
        for (int p = 0; p < 4; ++p) {
            int o = p * 4096 + tid * 16;
            gload16((const char*)(A  + (size_t)(bm + strow[p]) * 1024 + k0) + stcol[p], base + o);
            gload16((const char*)(WT + (size_t)(bn + strow[p]) * 1024 + k0) + stcol[p], base + 16384 + o);
        }
    };

    const int swz = (lr & 7) << 4;
    auto compute = [&](int buf) {
        const char* base = (const char*)SH + buf * 32768;
        bf8_t af[2][4], bfv[2][4];
        #pragma unroll
        for (int kk = 0; kk < 2; ++kk) {
            int col = (kk * 64 + lg * 16) ^ swz;
            #pragma unroll
            for (int i = 0; i < 4; ++i)
                af[kk][i] = *(const bf8_t*)(base + (wr * 64 + i * 16 + lr) * 128 + col);
            #pragma unroll
            for (int jj = 0; jj < 4; ++jj)
                bfv[kk][jj] = *(const bf8_t*)(base + 16384 + (wc * 64 + jj * 16 + lr) * 128 + col);
        }
        __builtin_amdgcn_s_setprio(1);
        #pragma unroll
        for (int kk = 0; kk < 2; ++kk)
            #pragma unroll
            for (int i = 0; i < 4; ++i)
                #pragma unroll
                for (int jj = 0; jj < 4; ++jj)
                    acc[i][jj] = MFMA16(af[kk][i], bfv[kk][jj], acc[i][jj]);
        __builtin_amdgcn_s_setprio(0);
    };

    stage(0, 0);
    __syncthreads();

    #pragma unroll 1
    for (int tt = 0; tt < 8; ++tt) {
        stage(1, (2 * tt + 1) * 64);
        compute(0);
        __syncthreads();
        if (tt < 7) stage(0, (2 * tt + 2) * 64);
        compute(1);
        __syncthreads();
    }

    if (MODE == 0) {
        const float* bias = (z == 0) ? b0 : (z == 1) ? b1 : b2;
        const float sc = (z == 0) ? 0.18033688011112042f : 1.0f; // 0.125*log2(e)
        const int bb = bm >> 11;
        const int sb = bm & 2047;

        if (z < 2) {
            #pragma unroll
            for (int i = 0; i < 4; ++i)
                #pragma unroll
                for (int jj = 0; jj < 4; ++jj) {
                    int c = wc * 64 + jj * 16 + lr;
                    float bcol = bias[bn + c];
                    #pragma unroll
                    for (int r = 0; r < 4; ++r) {
                        int s = wr * 64 + i * 16 + lg4 + r;
                        SH[s * 136 + c] = f2bf((acc[i][jj][r] + bcol) * sc);
                    }
                }
            __syncthreads();
            unsigned short* O = (unsigned short*)outp + (size_t)z * (8192 * 1024);
            #pragma unroll
            for (int it = 0; it < 8; ++it) {
                int idx = it * 256 + tid;
                int hh  = idx >> 10;
                int rem = idx & 1023;
                int ss  = rem >> 3;
                int cc  = rem & 7;
                u4_t v = *(const u4_t*)&SH[ss * 136 + hh * 64 + cc * 8];
                int hq = (bn >> 6) + hh;
                *(u4_t*)(O + (((size_t)(bb * 16 + hq)) * 2048 + sb + ss) * 64 + cc * 8) = v;
            }
        } else {
            // V^T: stage TRANSPOSED + key-permuted: SH[d_local][sp]
            #pragma unroll
            for (int i = 0; i < 4; ++i) {
                int spb = wr * 64 + 32 * (i >> 1) + 8 * lg + 4 * (i & 1);
                #pragma unroll
                for (int jj = 0; jj < 4; ++jj) {
                    int c = wc * 64 + jj * 16 + lr;
                    float bcol = bias[bn + c];
                    #pragma unroll
                    for (int r = 0; r < 4; ++r)
                        SH[c * 136 + spb + r] = f2bf(acc[i][jj][r] + bcol);
                }
            }
            __syncthreads();
            unsigned short* OT = (unsigned short*)outp2;
            #pragma unroll
            for (int it = 0; it < 8; ++it) {
                int idx  = it * 256 + tid;
                int drow = idx >> 4;
                int cc   = idx & 15;
                u4_t v = *(const u4_t*)&SH[drow * 136 + cc * 8];
                int dcol = bn + drow;
                int hq = dcol >> 6, dh = dcol & 63;
                *(u4_t*)(OT + (((size_t)(bb * 16 + hq)) * 64 + dh) * 2048 + sb + cc * 8) = v;
            }
        }
    } else {
        float* O = (float*)outp;
        float* SF = (float*)SH;
        #pragma unroll
        for (int hhalf = 0; hhalf < 2; ++hhalf) {
            if (wr == hhalf) {
                #pragma unroll
                for (int i = 0; i < 4; ++i)
                    #pragma unroll
                    for (int jj = 0; jj < 4; ++jj) {
                        int c = wc * 64 + jj * 16 + lr;
                        float bcol = b0[bn + c];
                        #pragma unroll
                        for (int r = 0; r < 4; ++r)
                            SF[(i * 16 + lg4 + r) * 132 + c] = acc[i][jj][r] + bcol;
                    }
            }
            __syncthreads();
            #pragma unroll
            for (int it = 0; it < 8; ++it) {
                int idx = it * 256 + tid;
                int ss  = idx >> 5;
                int cc  = idx & 31;
                u4_t v = *(const u4_t*)&SF[ss * 132 + cc * 4];
                *(u4_t*)(O + (size_t)(bm + hhalf * 64 + ss) * 1024 + bn + cc * 4) = v;
            }
            __syncthreads();
        }
    }
}

// ---------- flash attention: direct-exp2, MFMA denom, KVBLK=64 (R15 exact, proven) ----------
// setprio pairs are LOAD-BEARING here: R17 showed their removal lets the scheduler
// reorder across the gload_lds/barrier structure -> NaN. Do not remove without
// sched_barrier(0) pins at every barrier + race-screen.
// grid 512: 8 q-tiles x 64 heads, XCD-grouped. 4 waves x 64 q-rows (4 subtiles).
__global__ __launch_bounds__(256, 2) void k_attn(
    const unsigned short* __restrict__ Q,    // [64][2048][64], pre-scaled by 0.125*log2e
    const unsigned short* __restrict__ K,    // [64][2048][64]
    const unsigned short* __restrict__ VT,   // [64][64][2048], key-permuted per 64-block
    const float* __restrict__ fbias,         // [4][2048] 0/-1e30
    unsigned short* __restrict__ O)          // [8192][1024]
{
    __shared__ __align__(16) unsigned short Kls[2][64][64];  // [buf][key][d], XOR-swizzled
    __shared__ __align__(16) unsigned short Vls[2][64][64];  // [buf][d][pos], XOR-swizzled
    const int tid  = threadIdx.x;
    const int lane = tid & 63;
    const int w    = tid >> 6;
    const int lg   = lane >> 4, lr = lane & 15;
    const int lg4  = lg * 4;

    const int id = blockIdx.x;
    const int bh = (id & 7) * 8 + ((id >> 3) & 7);   // XCD (id&7) owns 8 heads
    const int qt = id >> 6;                           // 0..7
    const int b  = bh >> 4, h = bh & 15;
    const int q0 = qt * 256 + w * 64;
    const size_t base = (size_t)bh * (2048 * 64);

    const char* Kbase = (const char*)(K + base);
    const char* Vbase = (const char*)(VT + (size_t)bh * (64 * 2048));

    int srow[2], scol[2];
    #pragma unroll
    for (int p = 0; p < 2; ++p) {
        int o = p * 4096 + tid * 16;
        srow[p] = o >> 7;
        scol[p] = (o & 127) ^ ((srow[p] & 7) << 4);   // inverse swizzle on global src
    }

    auto stage = [&](int buf, int k0) {
        #pragma unroll
        for (int p = 0; p < 2; ++p) {
            int o = p * 4096 + tid * 16;
            gload16(Kbase + (size_t)(k0 + srow[p]) * 128 + scol[p],
                    (char*)&Kls[buf][0][0] + o);
            gload16(Vbase + (size_t)srow[p] * 4096 + (size_t)k0 * 2 + scol[p],
                    (char*)&Vls[buf][0][0] + o);
        }
    };

    // Q fragments, 4 subtiles (B-operand: lane holds Q[q=lr][dh=lg*8..])
    bf8_t qf[4][2];
    #pragma unroll
    for (int sub = 0; sub < 4; ++sub) {
        const unsigned short* qp = Q + base + (size_t)(q0 + sub * 16 + lr) * 64 + lg * 8;
        qf[sub][0] = *(const bf8_t*)qp;
        qf[sub][1] = *(const bf8_t*)(qp + 32);
    }

    const f4_t z4 = {0.f, 0.f, 0.f, 0.f};
    f4_t oacc[4][4];                 // [sub][nf]: O^T[d=nf*16+lg4+r][q=lr]
    #pragma unroll
    for (int sub = 0; sub < 4; ++sub)
        #pragma unroll
        for (int nf = 0; nf < 4; ++nf) oacc[sub][nf] = z4;
    f4_t lacc[4] = {z4, z4, z4, z4}; // denominator via MFMA(ones, P)

    u4_t uones = {0x3F803F80u, 0x3F803F80u, 0x3F803F80u, 0x3F803F80u};
    const bf8_t ones8 = __builtin_bit_cast(bf8_t, uones);

    const float* fb = fbias + b * 2048 + lg4;
    const int sw = (lr & 7) << 4;
    const int cA = (lg * 16) ^ sw;          // K frag cols
    const int cB = (64 + lg * 16) ^ sw;
    const int vA = (16 * lg) ^ sw;          // V frag cols (chunk 0 / 1)
    const int vB = (64 + 16 * lg) ^ sw;

    // direct softmax numerator: P = exp2(s); no max, no rescale, no cross-lane
    auto sm = [&](f4_t (&s)[4], u4_t (&pf)[2]) {
        #pragma unroll
        for (int c2 = 0; c2 < 2; ++c2) {
            float e0 = exp2_fast(s[2*c2][0]);
            float e1 = exp2_fast(s[2*c2][1]);
            float e2 = exp2_fast(s[2*c2][2]);
            float e3 = exp2_fast(s[2*c2][3]);
            float e4 = exp2_fast(s[2*c2+1][0]);
            float e5 = exp2_fast(s[2*c2+1][1]);
            float e6 = exp2_fast(s[2*c2+1][2]);
            float e7 = exp2_fast(s[2*c2+1][3]);
            u4_t u;
            u.x = cvtpk_bf16(e0, e1);
            u.y = cvtpk_bf16(e2, e3);
            u.z = cvtpk_bf16(e4, e5);
            u.w = cvtpk_bf16(e6, e7);
            pf[c2] = u;
        }
    };

    // tile body; cur passed as literal -> LDS addresses fold at compile time
    auto tile_body = [&](int cur, int k0) {
        f4_t cb[4];
        #pragma unroll
        for (int mf = 0; mf < 4; ++mf)
            cb[mf] = *(const f4_t*)(fb + k0 + mf * 16);

        bf8_t kf[4][2];
        #pragma unroll
        for (int mf = 0; mf < 4; ++mf) {
            const char* kr = (const char*)&Kls[cur][mf * 16 + lr][0];
            kf[mf][0] = *(const bf8_t*)(kr + cA);
            kf[mf][1] = *(const bf8_t*)(kr + cB);
        }
        bf8_t vf[4][2];
        #pragma unroll
        for (int nf = 0; nf < 4; ++nf) {
            const char* vr = (const char*)&Vls[cur][nf * 16 + lr][0];
            vf[nf][0] = *(const bf8_t*)(vr + vA);
            vf[nf][1] = *(const bf8_t*)(vr + vB);
        }

        // per-sub {QK -> exp2 -> PV}: sm(sub+1) VALU overlaps PV(sub) MFMA
        #pragma unroll
        for (int sub = 0; sub < 4; ++sub) {
            f4_t s[4];
            __builtin_amdgcn_s_setprio(1);
            #pragma unroll
            for (int mf = 0; mf < 4; ++mf)
                s[mf] = MFMA16(kf[mf][1], qf[sub][1], MFMA16(kf[mf][0], qf[sub][0], cb[mf]));
            __builtin_amdgcn_s_setprio(0);

            u4_t pf[2];
            sm(s, pf);

            __builtin_amdgcn_s_setprio(1);
            #pragma unroll
            for (int c = 0; c < 2; ++c) {
                bf8_t pb = __builtin_bit_cast(bf8_t, pf[c]);
                lacc[sub] = MFMA16(ones8, pb, lacc[sub]);
                #pragma unroll
                for (int nf = 0; nf < 4; ++nf)
                    oacc[sub][nf] = MFMA16(vf[nf][c], pb, oacc[sub][nf]);
            }
            __builtin_amdgcn_s_setprio(0);
        }
    };

    stage(0, 0);
    __syncthreads();

    #pragma unroll 1
    for (int tt = 0; tt < 16; ++tt) {
        stage(1, (2 * tt + 1) * 64);
        tile_body(0, 2 * tt * 64);
        __syncthreads();
        if (tt < 15) stage(0, (2 * tt + 2) * 64);
        tile_body(1, (2 * tt + 1) * 64);
        __syncthreads();
    }

    // normalize + write [B,S,D] bf16 (lane owns q=lr; no cross-lane reduce)
    #pragma unroll
    for (int sub = 0; sub < 4; ++sub) {
        float inv = 1.0f / lacc[sub][0];
        int qrow = q0 + sub * 16 + lr;
        size_t ob = ((size_t)(b * 2048 + qrow)) * 1024 + h * 64 + lg4;
        #pragma unroll
        for (int nf = 0; nf < 4; ++nf) {
            u2_t uo;
            uo.x = cvtpk_bf16(oacc[sub][nf][0] * inv, oacc[sub][nf][1] * inv);
            uo.y = cvtpk_bf16(oacc[sub][nf][2] * inv, oacc[sub][nf][3] * inv);
            *(u2_t*)(O + ob + nf * 16) = uo;
        }
    }
}

// ---------- launch ----------
extern "C" void kernel_launch(void* const* d_in, const int* in_sizes, int n_in,
                              void* d_out, int out_size, void* d_ws, size_t ws_size,
                              hipStream_t stream) {
    const float* x  = (const float*)d_in[0];
    const void*  mask = d_in[1];
    const float* Wq = (const float*)d_in[2];
    const float* bq = (const float*)d_in[3];
    const float* Wk = (const float*)d_in[4];
    const float* bk = (const float*)d_in[5];
    const float* Wv = (const float*)d_in[6];
    const float* bv = (const float*)d_in[7];
    const float* Wo = (const float*)d_in[8];
    const float* bo = (const float*)d_in[9];

    char* ws = (char*)d_ws;
    float*          fbias = (float*)(ws + 1024);
    unsigned short* xb    = (unsigned short*)(ws + 65536);                // 16 MiB
    unsigned short* wT    = (unsigned short*)(ws + 65536 + 16777216);     // 8 MiB
    unsigned short* qkv   = (unsigned short*)(ws + 65536 + 25165824);     // 48 MiB (Q,K,VT)
    unsigned short* attnb = (unsigned short*)(ws + 65536 + 75497472);     // 16 MiB

    unsigned short* Qb = qkv;
    unsigned short* Kb = qkv + 8388608;
    unsigned short* VT = qkv + 16777216;   // written (key-permuted) by GEMM z==2 epilogue

    k_prep<<<12289, 256, 0, stream>>>(x, xb, Wq, Wk, Wv, Wo, wT, mask, fbias);
    k_gemm<0><<<1536, 256, 0, stream>>>(xb, wT, bq, bk, bv, (void*)qkv, (void*)VT);
    k_attn<<<512, 256, 0, stream>>>(Qb, Kb, VT, fbias, attnb);
    k_gemm<1><<<512, 256, 0, stream>>>(attnb, wT + 3145728, bo, bo, bo, d_out, nullptr);
}